// Round 19
// baseline (140.319 us; speedup 1.0000x reference)
//
#include <hip/hip_runtime.h>
#include <hip/hip_bf16.h>
#include <stdint.h>

typedef __bf16 bf16;
typedef __bf16 bf16x4 __attribute__((ext_vector_type(4)));
typedef __bf16 bf16x8 __attribute__((ext_vector_type(8)));
typedef float f32x4 __attribute__((ext_vector_type(4)));
typedef float f32x8 __attribute__((ext_vector_type(8)));
typedef float f32x16 __attribute__((ext_vector_type(16)));
typedef unsigned int u32;
typedef u32 u32x4 __attribute__((ext_vector_type(4)));

#define MFMA16(a, b, c) __builtin_amdgcn_mfma_f32_16x16x32_bf16((a), (b), (c), 0, 0, 0)
#define MFMA32(a, b, c) __builtin_amdgcn_mfma_f32_32x32x16_bf16((a), (b), (c), 0, 0, 0)

#if __has_builtin(__builtin_amdgcn_exp2f)
#define EXP2(x) __builtin_amdgcn_exp2f(x)
#else
#define EXP2(x) exp2f(x)
#endif

__device__ __forceinline__ void async_copy16(const void* g, void* l) {
    __builtin_amdgcn_global_load_lds(
        (const __attribute__((address_space(1))) uint32_t*)g,
        (__attribute__((address_space(3))) uint32_t*)l,
        16, 0, 0);
}

__device__ __forceinline__ u32 cvt_pk_bf16(float lo, float hi) {
    u32 r;
    asm("v_cvt_pk_bf16_f32 %0, %1, %2" : "=v"(r) : "v"(lo), "v"(hi));
    return r;
}

// ---------------- fused cast: all five f32 tensors -> bf16 (Wq pre-scaled) ----------------
__global__ __launch_bounds__(256) void cast_all(const float* __restrict__ x,
                                                const float* __restrict__ wq,
                                                const float* __restrict__ wk,
                                                const float* __restrict__ wv,
                                                const float* __restrict__ wo,
                                                bf16* __restrict__ xb,
                                                bf16* __restrict__ wqk,
                                                bf16* __restrict__ wvb,
                                                bf16* __restrict__ wob,
                                                float qscale) {
    const int i = blockIdx.x * 256 + threadIdx.x;  // vec8 index, grid covers 1048576
    const float* src;
    bf16* dst;
    float scale = 1.0f;
    int j = i;
    if (j < 524288) {
        src = x; dst = xb;
    } else if ((j -= 524288) < 131072) {
        src = wq; dst = wqk; scale = qscale;
    } else if ((j -= 131072) < 131072) {
        src = wk; dst = wqk + 1024 * 1024;
    } else if ((j -= 131072) < 131072) {
        src = wv; dst = wvb;
    } else {
        j -= 131072;
        src = wo; dst = wob;
    }
    f32x8 v = *(const f32x8*)(src + (size_t)j * 8);
    bf16x8 o;
#pragma unroll
    for (int e = 0; e < 8; ++e) o[e] = (bf16)(v[e] * scale);
    *(bf16x8*)(dst + (size_t)j * 8) = o;
}

// ---------------- GEMM body: C[M,N] = A[M,K]*B[N,K]^T, 128x128 tile, BK=64 ----------------
// No setprio: barrier-lockstep waves (m190 + round-18 attn A/B: setprio hurts here).
template <typename CT>
__device__ __forceinline__ void gemm128_body(const bf16* __restrict__ A,
                                             const bf16* __restrict__ B,
                                             CT* __restrict__ C,
                                             int N, int K, int bx, int by,
                                             bf16* smem) {
    bf16* As = smem;                 // [2][128*64]
    bf16* Bs = smem + 2 * 128 * 64;  // [2][128*64]
    const int tid = threadIdx.x;
    const int wave = tid >> 6, lane = tid & 63;
    const int l4 = lane >> 4, l15 = lane & 15;
    const int wr = wave >> 1, wc = wave & 1;
    const size_t tM = (size_t)by * 128, tN = (size_t)bx * 128;

    f32x4 acc[4][4] = {};

    const int srowA = (lane & 7) * 16;
    auto stage = [&](int buf, int kt) {
#pragma unroll
        for (int c = 0; c < 4; ++c) {
            const int chunk = wave * 4 + c;
            const int row = chunk * 8 + (lane >> 3);
            const int scol = srowA ^ ((row & 7) << 4);
            const char* ga = (const char*)(A + (tM + row) * (size_t)K) + kt * 128 + scol;
            async_copy16(ga, (char*)(As + buf * 128 * 64) + chunk * 1024);
            const char* gb = (const char*)(B + (tN + row) * (size_t)K) + kt * 128 + scol;
            async_copy16(gb, (char*)(Bs + buf * 128 * 64) + chunk * 1024);
        }
    };
    auto lds_frag = [&](const bf16* base, int row, int colb) -> bf16x8 {
        const int addr = row * 128 + (colb ^ ((row & 7) << 4));
        return *(const bf16x8*)((const char*)base + addr);
    };

    const int nk = K >> 6;
    stage(0, 0);
    for (int kt = 0; kt < nk; ++kt) {
        const int buf = kt & 1;
        asm volatile("s_waitcnt vmcnt(0)" ::: "memory");
        __builtin_amdgcn_s_barrier();
        __builtin_amdgcn_sched_barrier(0);
        if (kt + 1 < nk) stage(buf ^ 1, kt + 1);

#pragma unroll
        for (int half = 0; half < 2; ++half) {
            bf16x8 aF[4], bF[4];
#pragma unroll
            for (int m = 0; m < 4; ++m)
                aF[m] = lds_frag(As + buf * 128 * 64, wr * 64 + m * 16 + l15, half * 64 + l4 * 16);
#pragma unroll
            for (int n = 0; n < 4; ++n)
                bF[n] = lds_frag(Bs + buf * 128 * 64, wc * 64 + n * 16 + l15, half * 64 + l4 * 16);
#pragma unroll
            for (int m = 0; m < 4; ++m)
#pragma unroll
                for (int n = 0; n < 4; ++n)
                    acc[m][n] = MFMA16(aF[m], bF[n], acc[m][n]);
        }
    }

#pragma unroll
    for (int m = 0; m < 4; ++m) {
        const size_t row0 = tM + wr * 64 + m * 16 + l4 * 4;
#pragma unroll
        for (int n = 0; n < 4; ++n) {
            const size_t col = tN + wc * 64 + n * 16 + l15;
#pragma unroll
            for (int r = 0; r < 4; ++r) {
                C[(row0 + r) * (size_t)N + col] = (CT)acc[m][n][r];
            }
        }
    }
}

// Fused dispatch: blocks 0-511 = QKV GEMM (4096x2048), blocks 512-767 = V^T GEMM
__global__ __launch_bounds__(256) void gemm_qkv_vt(const bf16* __restrict__ xb,
                                                   const bf16* __restrict__ wqk,
                                                   bf16* __restrict__ qkb,
                                                   const bf16* __restrict__ wvb,
                                                   bf16* __restrict__ vtb) {
    __shared__ bf16 smem[4 * 128 * 64];  // 64 KB
    int bid = blockIdx.x;
    if (bid < 512) {
        gemm128_body<bf16>(xb, wqk, qkb, 2048, 1024, bid & 15, bid >> 4, smem);
    } else {
        bid -= 512;
        gemm128_body<bf16>(wvb, xb, vtb, 4096, 1024, bid & 31, bid >> 5, smem);
    }
}

// ---------------- standalone BM=64 GEMM (output projection), no setprio ----------------
template <typename CT>
__global__ __launch_bounds__(256) void gemm_bt64(const bf16* __restrict__ A,
                                                 const bf16* __restrict__ B,
                                                 CT* __restrict__ C,
                                                 int M, int N, int K) {
    __shared__ bf16 As[2][64 * 64];
    __shared__ bf16 Bs[2][128 * 64];
    const int tid = threadIdx.x;
    const int wave = tid >> 6, lane = tid & 63;
    const int l4 = lane >> 4, l15 = lane & 15;
    const int wr = wave >> 1, wc = wave & 1;
    const int rb = wr * 32;
    const size_t tM = (size_t)blockIdx.y * 64, tN = (size_t)blockIdx.x * 128;

    f32x4 acc[2][4] = {};

    const int srowA = (lane & 7) * 16;
    auto stage = [&](int buf, int kt) {
#pragma unroll
        for (int c = 0; c < 2; ++c) {
            const int chunk = wave * 2 + c;
            const int row = chunk * 8 + (lane >> 3);
            const int scol = srowA ^ ((row & 7) << 4);
            const char* ga = (const char*)(A + (tM + row) * (size_t)K) + kt * 128 + scol;
            async_copy16(ga, (char*)&As[buf][0] + chunk * 1024);
        }
#pragma unroll
        for (int c = 0; c < 4; ++c) {
            const int chunk = wave * 4 + c;
            const int row = chunk * 8 + (lane >> 3);
            const int scol = srowA ^ ((row & 7) << 4);
            const char* gb = (const char*)(B + (tN + row) * (size_t)K) + kt * 128 + scol;
            async_copy16(gb, (char*)&Bs[buf][0] + chunk * 1024);
        }
    };
    auto lds_frag = [&](const bf16* base, int row, int colb) -> bf16x8 {
        const int addr = row * 128 + (colb ^ ((row & 7) << 4));
        return *(const bf16x8*)((const char*)base + addr);
    };

    const int nk = K >> 6;
    stage(0, 0);
    for (int kt = 0; kt < nk; ++kt) {
        const int buf = kt & 1;
        asm volatile("s_waitcnt vmcnt(0)" ::: "memory");
        __builtin_amdgcn_s_barrier();
        __builtin_amdgcn_sched_barrier(0);
        if (kt + 1 < nk) stage(buf ^ 1, kt + 1);

#pragma unroll
        for (int half = 0; half < 2; ++half) {
            bf16x8 aF[2], bF[4];
#pragma unroll
            for (int m = 0; m < 2; ++m)
                aF[m] = lds_frag(&As[buf][0], rb + m * 16 + l15, half * 64 + l4 * 16);
#pragma unroll
            for (int n = 0; n < 4; ++n)
                bF[n] = lds_frag(&Bs[buf][0], wc * 64 + n * 16 + l15, half * 64 + l4 * 16);
#pragma unroll
            for (int m = 0; m < 2; ++m)
#pragma unroll
                for (int n = 0; n < 4; ++n)
                    acc[m][n] = MFMA16(aF[m], bF[n], acc[m][n]);
        }
    }

#pragma unroll
    for (int m = 0; m < 2; ++m) {
        const size_t row0 = tM + rb + m * 16 + l4 * 4;
#pragma unroll
        for (int n = 0; n < 4; ++n) {
            const size_t col = tN + wc * 64 + n * 16 + l15;
#pragma unroll
            for (int r = 0; r < 4; ++r) {
                C[(row0 + r) * (size_t)N + col] = (CT)acc[m][n][r];
            }
        }
    }
}

// ---------------- flash attention (round-18 version: best measured, 84.6 us) ----------------
__global__ __launch_bounds__(256, 2) void attn_kernel(const bf16* __restrict__ qk,
                                                      const bf16* __restrict__ vt,
                                                      bf16* __restrict__ out) {
    const int b = blockIdx.x;
    const int h = (b & 7) * 2 + ((b >> 3) & 1);
    const int qb = b >> 4;
    const int tid = threadIdx.x;
    const int wave = tid >> 6, lane = tid & 63;
    const int l31 = lane & 31, hi = lane >> 5;

    __shared__ bf16 Kt[4][64 * 64];
    __shared__ bf16 Vs[4][64 * 64];

    const int qrow = qb * 128 + wave * 32 + l31;
    const bf16* qptr = qk + (size_t)qrow * 2048 + h * 64 + hi * 8;
    bf16x8 qf[4];
#pragma unroll
    for (int kd = 0; kd < 4; ++kd) qf[kd] = *(const bf16x8*)(qptr + kd * 16);
    asm volatile("s_waitcnt vmcnt(0)" ::: "memory");

    const bf16* Kg = qk + 1024 + h * 64;                // row stride 2048 elems
    const bf16* Vg = vt + (size_t)(h * 64) * 4096;      // row stride 4096 elems

    f32x16 o0 = {}, o1 = {};
    float lrun = 0.f;                                   // lane-local partial sum

    const int srow = (tid & 7) * 16;

    auto stage = [&](int buf, int t) {
        const int kv0 = t * 64;
#pragma unroll
        for (int c = 0; c < 2; ++c) {
            const int row = c * 32 + (tid >> 3);                 // 0..63
            const int scol = srow ^ ((row & 7) << 4);            // swizzled byte col
            const bf16* gk = Kg + (size_t)(kv0 + row) * 2048 + (scol >> 1);
            async_copy16(gk, (char*)&Kt[buf][0] + c * 4096 + wave * 1024);
            const bf16* gv = Vg + (size_t)row * 4096 + kv0 + (scol >> 1);
            async_copy16(gv, (char*)&Vs[buf][0] + c * 4096 + wave * 1024);
        }
    };

    auto lds_b128 = [&](const bf16* base, int row, int colb) -> bf16x8 {
        const int addr = row * 128 + (colb ^ ((row & 7) << 4));
        return *(const bf16x8*)((const char*)base + addr);
    };
    auto lds_b64 = [&](const bf16* base, int row, int colb) -> bf16x4 {
        const int addr = row * 128 + (colb ^ ((row & 7) << 4));
        return *(const bf16x4*)((const char*)base + addr);
    };

    // one 64-kv tile body; buf is a compile-time literal at every call site
    auto body = [&](int buf) {
        f32x16 s0 = {}, s1 = {};
#pragma unroll
        for (int kd = 0; kd < 4; ++kd) {
            bf16x8 k0 = lds_b128(&Kt[buf][0], l31, hi * 16 + kd * 32);
            bf16x8 k1 = lds_b128(&Kt[buf][0], 32 + l31, hi * 16 + kd * 32);
            s0 = MFMA32(k0, qf[kd], s0);
            s1 = MFMA32(k1, qf[kd], s1);
        }

        float p0[16], p1[16];
#pragma unroll
        for (int i = 0; i < 16; ++i) p0[i] = EXP2(s0[i]);
#pragma unroll
        for (int i = 0; i < 16; ++i) p1[i] = EXP2(s1[i]);
        {
            float a0 = 0.f, a1 = 0.f, a2 = 0.f, a3 = 0.f;
#pragma unroll
            for (int i = 0; i < 4; ++i) {
                a0 += p0[i] + p0[8 + i];
                a1 += p0[4 + i] + p0[12 + i];
                a2 += p1[i] + p1[8 + i];
                a3 += p1[4 + i] + p1[12 + i];
            }
            lrun += (a0 + a1) + (a2 + a3);   // cross-lane reduce deferred to epilogue
        }

        u32 pw0[8], pw1[8];
#pragma unroll
        for (int t2 = 0; t2 < 8; ++t2) {
            pw0[t2] = cvt_pk_bf16(p0[2 * t2], p0[2 * t2 + 1]);
            pw1[t2] = cvt_pk_bf16(p1[2 * t2], p1[2 * t2 + 1]);
        }

#pragma unroll
        for (int j = 0; j < 4; ++j) {
            const u32* pw = (j & 2) ? pw1 : pw0;
            const int o = (j & 1) * 4;
            u32x4 fr = {pw[o + 0], pw[o + 1], pw[o + 2], pw[o + 3]};
            const bf16x8 pf = __builtin_bit_cast(bf16x8, fr);
            const int c0 = 32 * j + 8 * hi;
            bf16x4 va = lds_b64(&Vs[buf][0], l31, c0);
            bf16x4 vb = lds_b64(&Vs[buf][0], l31, c0 + 16);
            bf16x4 vc = lds_b64(&Vs[buf][0], 32 + l31, c0);
            bf16x4 vd = lds_b64(&Vs[buf][0], 32 + l31, c0 + 16);
            const bf16x8 v0f = __builtin_shufflevector(va, vb, 0, 1, 2, 3, 4, 5, 6, 7);
            const bf16x8 v1f = __builtin_shufflevector(vc, vd, 0, 1, 2, 3, 4, 5, 6, 7);
            o0 = MFMA32(v0f, pf, o0);
            o1 = MFMA32(v1f, pf, o1);
        }
    };

    stage(0, 0);
    stage(1, 1);
    for (int pp = 0; pp < 16; ++pp) {
        const int base = 4 * pp;
        // ---- pair A (tiles base+0, base+1 in bufs 0,1)
        asm volatile("s_waitcnt vmcnt(0)" ::: "memory");
        __builtin_amdgcn_s_barrier();
        __builtin_amdgcn_sched_barrier(0);
        stage(2, base + 2);
        stage(3, base + 3);
        body(0);
        body(1);
        // ---- pair B (tiles base+2, base+3 in bufs 2,3)
        asm volatile("s_waitcnt vmcnt(0)" ::: "memory");
        __builtin_amdgcn_s_barrier();
        __builtin_amdgcn_sched_barrier(0);
        if (pp < 15) {
            stage(0, base + 4);
            stage(1, base + 5);
        }
        body(2);
        body(3);
    }

    // ---- epilogue: single cross-lane reduction, then normalize + store
    lrun += __shfl_xor(lrun, 32, 64);
    const float inv = 1.0f / lrun;
#pragma unroll
    for (int dt = 0; dt < 2; ++dt) {
        const f32x16& oo = dt ? o1 : o0;
#pragma unroll
        for (int g = 0; g < 4; ++g) {
            const u32 lo = cvt_pk_bf16(oo[4 * g + 0] * inv, oo[4 * g + 1] * inv);
            const u32 hi2 = cvt_pk_bf16(oo[4 * g + 2] * inv, oo[4 * g + 3] * inv);
            const int d0 = dt * 32 + 8 * g + 4 * hi;
            *(uint2*)(out + (size_t)qrow * 1024 + h * 64 + d0) = make_uint2(lo, hi2);
        }
    }
}

extern "C" void kernel_launch(void* const* d_in, const int* in_sizes, int n_in,
                              void* d_out, int out_size, void* d_ws, size_t ws_size,
                              hipStream_t stream) {
    const float* x = (const float*)d_in[0];
    const float* wq = (const float*)d_in[1];
    const float* wk = (const float*)d_in[2];
    const float* wv = (const float*)d_in[3];
    const float* wo = (const float*)d_in[4];
    float* out = (float*)d_out;

    char* ws = (char*)d_ws;
    bf16* xb = (bf16*)(ws);                   // 4096x1024 (8 MB)
    bf16* wqk = (bf16*)(ws + (8u << 20));     // 2048x1024 (4 MB): Wq (scaled), Wk
    bf16* wvb = (bf16*)(ws + (12u << 20));    // 1024x1024 (2 MB)
    bf16* wob = (bf16*)(ws + (14u << 20));    // 1024x1024 (2 MB)
    bf16* qkb = (bf16*)(ws + (16u << 20));    // 4096x2048 (16 MB)
    bf16* vtb = (bf16*)(ws + (32u << 20));    // 1024x4096 (8 MB) = V^T
    bf16* attno = xb;                         // reuse after projections

    const float qscale = 0.125f * 1.44269504089f;  // 1/sqrt(64) * log2(e)
    cast_all<<<4096, 256, 0, stream>>>(x, wq, wk, wv, wo, xb, wqk, wvb, wob, qscale);

    // fused: [Q K] = xb @ wqk^T (blocks 0-511) || V^T = wvb @ xb^T (blocks 512-767)
    gemm_qkv_vt<<<768, 256, 0, stream>>>(xb, wqk, qkb, wvb, vtb);
    // attention -> attno [4096, 1024] bf16
    attn_kernel<<<512, 256, 0, stream>>>(qkb, vtb, attno);
    // out = attno @ wob^T : [4096, 1024] f32
    gemm_bt64<float><<<dim3(8, 64), 256, 0, stream>>>(attno, wob, out, 4096, 1024, 1024);
}

// Round 20
// 136.764 us; speedup vs baseline: 1.0260x; 1.0260x over previous
//
#include <hip/hip_runtime.h>
#include <hip/hip_bf16.h>
#include <stdint.h>

typedef __bf16 bf16;
typedef __bf16 bf16x4 __attribute__((ext_vector_type(4)));
typedef __bf16 bf16x8 __attribute__((ext_vector_type(8)));
typedef float f32x4 __attribute__((ext_vector_type(4)));
typedef float f32x8 __attribute__((ext_vector_type(8)));
typedef float f32x16 __attribute__((ext_vector_type(16)));
typedef unsigned int u32;
typedef u32 u32x4 __attribute__((ext_vector_type(4)));

#define MFMA16(a, b, c) __builtin_amdgcn_mfma_f32_16x16x32_bf16((a), (b), (c), 0, 0, 0)
#define MFMA32(a, b, c) __builtin_amdgcn_mfma_f32_32x32x16_bf16((a), (b), (c), 0, 0, 0)

#if __has_builtin(__builtin_amdgcn_exp2f)
#define EXP2(x) __builtin_amdgcn_exp2f(x)
#else
#define EXP2(x) exp2f(x)
#endif

__device__ __forceinline__ void async_copy16(const void* g, void* l) {
    __builtin_amdgcn_global_load_lds(
        (const __attribute__((address_space(1))) uint32_t*)g,
        (__attribute__((address_space(3))) uint32_t*)l,
        16, 0, 0);
}

__device__ __forceinline__ u32 cvt_pk_bf16(float lo, float hi) {
    u32 r;
    asm("v_cvt_pk_bf16_f32 %0, %1, %2" : "=v"(r) : "v"(lo), "v"(hi));
    return r;
}

// ---------------- fused cast: all five f32 tensors -> bf16 (Wq pre-scaled) ----------------
__global__ __launch_bounds__(256) void cast_all(const float* __restrict__ x,
                                                const float* __restrict__ wq,
                                                const float* __restrict__ wk,
                                                const float* __restrict__ wv,
                                                const float* __restrict__ wo,
                                                bf16* __restrict__ xb,
                                                bf16* __restrict__ wqk,
                                                bf16* __restrict__ wvb,
                                                bf16* __restrict__ wob,
                                                float qscale) {
    const int i = blockIdx.x * 256 + threadIdx.x;  // vec8 index, grid covers 1048576
    const float* src;
    bf16* dst;
    float scale = 1.0f;
    int j = i;
    if (j < 524288) {
        src = x; dst = xb;
    } else if ((j -= 524288) < 131072) {
        src = wq; dst = wqk; scale = qscale;
    } else if ((j -= 131072) < 131072) {
        src = wk; dst = wqk + 1024 * 1024;
    } else if ((j -= 131072) < 131072) {
        src = wv; dst = wvb;
    } else {
        j -= 131072;
        src = wo; dst = wob;
    }
    f32x8 v = *(const f32x8*)(src + (size_t)j * 8);
    bf16x8 o;
#pragma unroll
    for (int e = 0; e < 8; ++e) o[e] = (bf16)(v[e] * scale);
    *(bf16x8*)(dst + (size_t)j * 8) = o;
}

// ---------------- GEMM body: C[M,N] = A[M,K]*B[N,K]^T, 128x128 tile, BK=64 ----------------
// setprio KEPT here (r19 A/B: removing it cost ~3.5 us — GEMM co-resident waves are
// phase-independent across blocks, the T5-favorable regime; attn's lockstep is not).
template <typename CT>
__device__ __forceinline__ void gemm128_body(const bf16* __restrict__ A,
                                             const bf16* __restrict__ B,
                                             CT* __restrict__ C,
                                             int N, int K, int bx, int by,
                                             bf16* smem) {
    bf16* As = smem;                 // [2][128*64]
    bf16* Bs = smem + 2 * 128 * 64;  // [2][128*64]
    const int tid = threadIdx.x;
    const int wave = tid >> 6, lane = tid & 63;
    const int l4 = lane >> 4, l15 = lane & 15;
    const int wr = wave >> 1, wc = wave & 1;
    const size_t tM = (size_t)by * 128, tN = (size_t)bx * 128;

    f32x4 acc[4][4] = {};

    const int srowA = (lane & 7) * 16;
    auto stage = [&](int buf, int kt) {
#pragma unroll
        for (int c = 0; c < 4; ++c) {
            const int chunk = wave * 4 + c;
            const int row = chunk * 8 + (lane >> 3);
            const int scol = srowA ^ ((row & 7) << 4);
            const char* ga = (const char*)(A + (tM + row) * (size_t)K) + kt * 128 + scol;
            async_copy16(ga, (char*)(As + buf * 128 * 64) + chunk * 1024);
            const char* gb = (const char*)(B + (tN + row) * (size_t)K) + kt * 128 + scol;
            async_copy16(gb, (char*)(Bs + buf * 128 * 64) + chunk * 1024);
        }
    };
    auto lds_frag = [&](const bf16* base, int row, int colb) -> bf16x8 {
        const int addr = row * 128 + (colb ^ ((row & 7) << 4));
        return *(const bf16x8*)((const char*)base + addr);
    };

    const int nk = K >> 6;
    stage(0, 0);
    for (int kt = 0; kt < nk; ++kt) {
        const int buf = kt & 1;
        asm volatile("s_waitcnt vmcnt(0)" ::: "memory");
        __builtin_amdgcn_s_barrier();
        __builtin_amdgcn_sched_barrier(0);
        if (kt + 1 < nk) stage(buf ^ 1, kt + 1);

#pragma unroll
        for (int half = 0; half < 2; ++half) {
            bf16x8 aF[4], bF[4];
#pragma unroll
            for (int m = 0; m < 4; ++m)
                aF[m] = lds_frag(As + buf * 128 * 64, wr * 64 + m * 16 + l15, half * 64 + l4 * 16);
#pragma unroll
            for (int n = 0; n < 4; ++n)
                bF[n] = lds_frag(Bs + buf * 128 * 64, wc * 64 + n * 16 + l15, half * 64 + l4 * 16);
            __builtin_amdgcn_s_setprio(1);
#pragma unroll
            for (int m = 0; m < 4; ++m)
#pragma unroll
                for (int n = 0; n < 4; ++n)
                    acc[m][n] = MFMA16(aF[m], bF[n], acc[m][n]);
            __builtin_amdgcn_s_setprio(0);
        }
    }

#pragma unroll
    for (int m = 0; m < 4; ++m) {
        const size_t row0 = tM + wr * 64 + m * 16 + l4 * 4;
#pragma unroll
        for (int n = 0; n < 4; ++n) {
            const size_t col = tN + wc * 64 + n * 16 + l15;
#pragma unroll
            for (int r = 0; r < 4; ++r) {
                C[(row0 + r) * (size_t)N + col] = (CT)acc[m][n][r];
            }
        }
    }
}

// Fused dispatch: blocks 0-511 = QKV GEMM (4096x2048), blocks 512-767 = V^T GEMM
__global__ __launch_bounds__(256) void gemm_qkv_vt(const bf16* __restrict__ xb,
                                                   const bf16* __restrict__ wqk,
                                                   bf16* __restrict__ qkb,
                                                   const bf16* __restrict__ wvb,
                                                   bf16* __restrict__ vtb) {
    __shared__ bf16 smem[4 * 128 * 64];  // 64 KB
    int bid = blockIdx.x;
    if (bid < 512) {
        gemm128_body<bf16>(xb, wqk, qkb, 2048, 1024, bid & 15, bid >> 4, smem);
    } else {
        bid -= 512;
        gemm128_body<bf16>(wvb, xb, vtb, 4096, 1024, bid & 31, bid >> 5, smem);
    }
}

// ---------------- standalone BM=64 GEMM (output projection), setprio kept ----------------
template <typename CT>
__global__ __launch_bounds__(256) void gemm_bt64(const bf16* __restrict__ A,
                                                 const bf16* __restrict__ B,
                                                 CT* __restrict__ C,
                                                 int M, int N, int K) {
    __shared__ bf16 As[2][64 * 64];
    __shared__ bf16 Bs[2][128 * 64];
    const int tid = threadIdx.x;
    const int wave = tid >> 6, lane = tid & 63;
    const int l4 = lane >> 4, l15 = lane & 15;
    const int wr = wave >> 1, wc = wave & 1;
    const int rb = wr * 32;
    const size_t tM = (size_t)blockIdx.y * 64, tN = (size_t)blockIdx.x * 128;

    f32x4 acc[2][4] = {};

    const int srowA = (lane & 7) * 16;
    auto stage = [&](int buf, int kt) {
#pragma unroll
        for (int c = 0; c < 2; ++c) {
            const int chunk = wave * 2 + c;
            const int row = chunk * 8 + (lane >> 3);
            const int scol = srowA ^ ((row & 7) << 4);
            const char* ga = (const char*)(A + (tM + row) * (size_t)K) + kt * 128 + scol;
            async_copy16(ga, (char*)&As[buf][0] + chunk * 1024);
        }
#pragma unroll
        for (int c = 0; c < 4; ++c) {
            const int chunk = wave * 4 + c;
            const int row = chunk * 8 + (lane >> 3);
            const int scol = srowA ^ ((row & 7) << 4);
            const char* gb = (const char*)(B + (tN + row) * (size_t)K) + kt * 128 + scol;
            async_copy16(gb, (char*)&Bs[buf][0] + chunk * 1024);
        }
    };
    auto lds_frag = [&](const bf16* base, int row, int colb) -> bf16x8 {
        const int addr = row * 128 + (colb ^ ((row & 7) << 4));
        return *(const bf16x8*)((const char*)base + addr);
    };

    const int nk = K >> 6;
    stage(0, 0);
    for (int kt = 0; kt < nk; ++kt) {
        const int buf = kt & 1;
        asm volatile("s_waitcnt vmcnt(0)" ::: "memory");
        __builtin_amdgcn_s_barrier();
        __builtin_amdgcn_sched_barrier(0);
        if (kt + 1 < nk) stage(buf ^ 1, kt + 1);

#pragma unroll
        for (int half = 0; half < 2; ++half) {
            bf16x8 aF[2], bF[4];
#pragma unroll
            for (int m = 0; m < 2; ++m)
                aF[m] = lds_frag(&As[buf][0], rb + m * 16 + l15, half * 64 + l4 * 16);
#pragma unroll
            for (int n = 0; n < 4; ++n)
                bF[n] = lds_frag(&Bs[buf][0], wc * 64 + n * 16 + l15, half * 64 + l4 * 16);
            __builtin_amdgcn_s_setprio(1);
#pragma unroll
            for (int m = 0; m < 2; ++m)
#pragma unroll
                for (int n = 0; n < 4; ++n)
                    acc[m][n] = MFMA16(aF[m], bF[n], acc[m][n]);
            __builtin_amdgcn_s_setprio(0);
        }
    }

#pragma unroll
    for (int m = 0; m < 2; ++m) {
        const size_t row0 = tM + rb + m * 16 + l4 * 4;
#pragma unroll
        for (int n = 0; n < 4; ++n) {
            const size_t col = tN + wc * 64 + n * 16 + l15;
#pragma unroll
            for (int r = 0; r < 4; ++r) {
                C[(row0 + r) * (size_t)N + col] = (CT)acc[m][n][r];
            }
        }
    }
}

// ---------------- flash attention (round-18 version: best measured, 84.6 us) ----------------
// No setprio (r18 A/B: +8% from removal on this lockstep structure).
__global__ __launch_bounds__(256, 2) void attn_kernel(const bf16* __restrict__ qk,
                                                      const bf16* __restrict__ vt,
                                                      bf16* __restrict__ out) {
    const int b = blockIdx.x;
    const int h = (b & 7) * 2 + ((b >> 3) & 1);
    const int qb = b >> 4;
    const int tid = threadIdx.x;
    const int wave = tid >> 6, lane = tid & 63;
    const int l31 = lane & 31, hi = lane >> 5;

    __shared__ bf16 Kt[4][64 * 64];
    __shared__ bf16 Vs[4][64 * 64];

    const int qrow = qb * 128 + wave * 32 + l31;
    const bf16* qptr = qk + (size_t)qrow * 2048 + h * 64 + hi * 8;
    bf16x8 qf[4];
#pragma unroll
    for (int kd = 0; kd < 4; ++kd) qf[kd] = *(const bf16x8*)(qptr + kd * 16);
    asm volatile("s_waitcnt vmcnt(0)" ::: "memory");

    const bf16* Kg = qk + 1024 + h * 64;                // row stride 2048 elems
    const bf16* Vg = vt + (size_t)(h * 64) * 4096;      // row stride 4096 elems

    f32x16 o0 = {}, o1 = {};
    float lrun = 0.f;                                   // lane-local partial sum

    const int srow = (tid & 7) * 16;

    auto stage = [&](int buf, int t) {
        const int kv0 = t * 64;
#pragma unroll
        for (int c = 0; c < 2; ++c) {
            const int row = c * 32 + (tid >> 3);                 // 0..63
            const int scol = srow ^ ((row & 7) << 4);            // swizzled byte col
            const bf16* gk = Kg + (size_t)(kv0 + row) * 2048 + (scol >> 1);
            async_copy16(gk, (char*)&Kt[buf][0] + c * 4096 + wave * 1024);
            const bf16* gv = Vg + (size_t)row * 4096 + kv0 + (scol >> 1);
            async_copy16(gv, (char*)&Vs[buf][0] + c * 4096 + wave * 1024);
        }
    };

    auto lds_b128 = [&](const bf16* base, int row, int colb) -> bf16x8 {
        const int addr = row * 128 + (colb ^ ((row & 7) << 4));
        return *(const bf16x8*)((const char*)base + addr);
    };
    auto lds_b64 = [&](const bf16* base, int row, int colb) -> bf16x4 {
        const int addr = row * 128 + (colb ^ ((row & 7) << 4));
        return *(const bf16x4*)((const char*)base + addr);
    };

    // one 64-kv tile body; buf is a compile-time literal at every call site
    auto body = [&](int buf) {
        f32x16 s0 = {}, s1 = {};
#pragma unroll
        for (int kd = 0; kd < 4; ++kd) {
            bf16x8 k0 = lds_b128(&Kt[buf][0], l31, hi * 16 + kd * 32);
            bf16x8 k1 = lds_b128(&Kt[buf][0], 32 + l31, hi * 16 + kd * 32);
            s0 = MFMA32(k0, qf[kd], s0);
            s1 = MFMA32(k1, qf[kd], s1);
        }

        float p0[16], p1[16];
#pragma unroll
        for (int i = 0; i < 16; ++i) p0[i] = EXP2(s0[i]);
#pragma unroll
        for (int i = 0; i < 16; ++i) p1[i] = EXP2(s1[i]);
        {
            float a0 = 0.f, a1 = 0.f, a2 = 0.f, a3 = 0.f;
#pragma unroll
            for (int i = 0; i < 4; ++i) {
                a0 += p0[i] + p0[8 + i];
                a1 += p0[4 + i] + p0[12 + i];
                a2 += p1[i] + p1[8 + i];
                a3 += p1[4 + i] + p1[12 + i];
            }
            lrun += (a0 + a1) + (a2 + a3);   // cross-lane reduce deferred to epilogue
        }

        u32 pw0[8], pw1[8];
#pragma unroll
        for (int t2 = 0; t2 < 8; ++t2) {
            pw0[t2] = cvt_pk_bf16(p0[2 * t2], p0[2 * t2 + 1]);
            pw1[t2] = cvt_pk_bf16(p1[2 * t2], p1[2 * t2 + 1]);
        }

#pragma unroll
        for (int j = 0; j < 4; ++j) {
            const u32* pw = (j & 2) ? pw1 : pw0;
            const int o = (j & 1) * 4;
            u32x4 fr = {pw[o + 0], pw[o + 1], pw[o + 2], pw[o + 3]};
            const bf16x8 pf = __builtin_bit_cast(bf16x8, fr);
            const int c0 = 32 * j + 8 * hi;
            bf16x4 va = lds_b64(&Vs[buf][0], l31, c0);
            bf16x4 vb = lds_b64(&Vs[buf][0], l31, c0 + 16);
            bf16x4 vc = lds_b64(&Vs[buf][0], 32 + l31, c0);
            bf16x4 vd = lds_b64(&Vs[buf][0], 32 + l31, c0 + 16);
            const bf16x8 v0f = __builtin_shufflevector(va, vb, 0, 1, 2, 3, 4, 5, 6, 7);
            const bf16x8 v1f = __builtin_shufflevector(vc, vd, 0, 1, 2, 3, 4, 5, 6, 7);
            o0 = MFMA32(v0f, pf, o0);
            o1 = MFMA32(v1f, pf, o1);
        }
    };

    stage(0, 0);
    stage(1, 1);
    for (int pp = 0; pp < 16; ++pp) {
        const int base = 4 * pp;
        // ---- pair A (tiles base+0, base+1 in bufs 0,1)
        asm volatile("s_waitcnt vmcnt(0)" ::: "memory");
        __builtin_amdgcn_s_barrier();
        __builtin_amdgcn_sched_barrier(0);
        stage(2, base + 2);
        stage(3, base + 3);
        body(0);
        body(1);
        // ---- pair B (tiles base+2, base+3 in bufs 2,3)
        asm volatile("s_waitcnt vmcnt(0)" ::: "memory");
        __builtin_amdgcn_s_barrier();
        __builtin_amdgcn_sched_barrier(0);
        if (pp < 15) {
            stage(0, base + 4);
            stage(1, base + 5);
        }
        body(2);
        body(3);
    }

    // ---- epilogue: single cross-lane reduction, then normalize + store
    lrun += __shfl_xor(lrun, 32, 64);
    const float inv = 1.0f / lrun;
#pragma unroll
    for (int dt = 0; dt < 2; ++dt) {
        const f32x16& oo = dt ? o1 : o0;
#pragma unroll
        for (int g = 0; g < 4; ++g) {
            const u32 lo = cvt_pk_bf16(oo[4 * g + 0] * inv, oo[4 * g + 1] * inv);
            const u32 hi2 = cvt_pk_bf16(oo[4 * g + 2] * inv, oo[4 * g + 3] * inv);
            const int d0 = dt * 32 + 8 * g + 4 * hi;
            *(uint2*)(out + (size_t)qrow * 1024 + h * 64 + d0) = make_uint2(lo, hi2);
        }
    }
}

extern "C" void kernel_launch(void* const* d_in, const int* in_sizes, int n_in,
                              void* d_out, int out_size, void* d_ws, size_t ws_size,
                              hipStream_t stream) {
    const float* x = (const float*)d_in[0];
    const float* wq = (const float*)d_in[1];
    const float* wk = (const float*)d_in[2];
    const float* wv = (const float*)d_in[3];
    const float* wo = (const float*)d_in[4];
    float* out = (float*)d_out;

    char* ws = (char*)d_ws;
    bf16* xb = (bf16*)(ws);                   // 4096x1024 (8 MB)
    bf16* wqk = (bf16*)(ws + (8u << 20));     // 2048x1024 (4 MB): Wq (scaled), Wk
    bf16* wvb = (bf16*)(ws + (12u << 20));    // 1024x1024 (2 MB)
    bf16* wob = (bf16*)(ws + (14u << 20));    // 1024x1024 (2 MB)
    bf16* qkb = (bf16*)(ws + (16u << 20));    // 4096x2048 (16 MB)
    bf16* vtb = (bf16*)(ws + (32u << 20));    // 1024x4096 (8 MB) = V^T
    bf16* attno = xb;                         // reuse after projections

    const float qscale = 0.125f * 1.44269504089f;  // 1/sqrt(64) * log2(e)
    cast_all<<<4096, 256, 0, stream>>>(x, wq, wk, wv, wo, xb, wqk, wvb, wob, qscale);

    // fused: [Q K] = xb @ wqk^T (blocks 0-511) || V^T = wvb @ xb^T (blocks 512-767)
    gemm_qkv_vt<<<768, 256, 0, stream>>>(xb, wqk, qkb, wvb, vtb);
    // attention -> attno [4096, 1024] bf16
    attn_kernel<<<512, 256, 0, stream>>>(qkb, vtb, attno);
    // out = attno @ wob^T : [4096, 1024] f32
    gemm_bt64<float><<<dim3(8, 64), 256, 0, stream>>>(attno, wob, out, 4096, 1024, 1024);
}